// Round 1
// 181.563 us; speedup vs baseline: 1.0105x; 1.0105x over previous
//
#include <hip/hip_runtime.h>
#include <math.h>

#define IMG_H 512
#define IMG_W 512
#define IMG_HW (IMG_H * IMG_W)

namespace {

// float32-rounded cos(k*pi/16) values
constexpr float CFv[9] = {
    1.0f,
    0.98078528040323044913f,
    0.92387953251128675613f,
    0.83146961230254523708f,
    0.70710678118654752440f,
    0.55557023301960222474f,
    0.38268343236508977173f,
    0.19509032201612826785f,
    0.0f
};

struct CTab {
    float  cf[8][8];     // C[x][u] = f32(cos((2x+1)u pi/16))
    double cd[8][8];     // promoted to double
    float  aof[8][8];    // ALPHA outer product (f32)
    float  scalef[8][8]; // DCT_SCALE = ALPHA*0.25
};

constexpr CTab make_ctab() {
    CTab t{};
    for (int y = 0; y < 8; y++) {
        for (int v = 0; v < 8; v++) {
            int a = ((2 * y + 1) * v) & 31;
            if (a > 16) a = 32 - a;
            float val = (a <= 8) ? CFv[a] : -CFv[16 - a];
            t.cf[y][v] = val;
            t.cd[y][v] = (double)val;
        }
    }
    constexpr float A0 = 0.70710678118654752440f;
    for (int u = 0; u < 8; u++) {
        for (int v = 0; v < 8; v++) {
            float au = (u == 0) ? A0 : 1.0f;
            float av = (v == 0) ? A0 : 1.0f;
            float ao = au * av;
            t.aof[u][v] = ao;
            t.scalef[u][v] = ao * 0.25f;
        }
    }
    return t;
}

constexpr CTab CT = make_ctab();

// forward 8-pt pass (fp64), even/odd butterfly: s[v] = sum_y a[y]*cd[y][v]
// (uses cd[7-y][v] = +/-cd[y][v]; association change is fp64-only -> harmless)
__device__ __forceinline__ void fwd8_d(const double a[8], double s[8]) {
    double e0 = a[0] + a[7], e1 = a[1] + a[6], e2 = a[2] + a[5], e3 = a[3] + a[4];
    double o0 = a[0] - a[7], o1 = a[1] - a[6], o2 = a[2] - a[5], o3 = a[3] - a[4];
    double ee0 = e0 + e3, ee1 = e1 + e2, eo0 = e0 - e3, eo1 = e1 - e2;
    s[0] = ee0 + ee1;
    s[4] = (ee0 - ee1) * CT.cd[0][4];
    s[2] = eo0 * CT.cd[0][2] + eo1 * CT.cd[1][2];
    s[6] = eo0 * CT.cd[0][6] + eo1 * CT.cd[1][6];
    #pragma unroll
    for (int k = 0; k < 4; k++) {
        const int v = 2 * k + 1;
        s[v] = o0 * CT.cd[0][v] + o1 * CT.cd[1][v] + o2 * CT.cd[2][v] + o3 * CT.cd[3][v];
    }
}

// inverse 8-pt pass (fp32), output-symmetry butterfly: m[x] = sum_u d[u]*cf[x][u]
__device__ __forceinline__ void inv8_f(const float d[8], float m[8]) {
    float eea = fmaf(CT.cf[0][4], d[4], d[0]);
    float eeb = fmaf(CT.cf[1][4], d[4], d[0]);
    float u2a = d[2] * CT.cf[0][2] + d[6] * CT.cf[0][6];
    float u2b = d[2] * CT.cf[1][2] + d[6] * CT.cf[1][6];
    float E0 = eea + u2a, E1 = eeb + u2b, E2 = eeb - u2b, E3 = eea - u2a;
    float O0 = d[1] * CT.cf[0][1] + d[3] * CT.cf[0][3] + d[5] * CT.cf[0][5] + d[7] * CT.cf[0][7];
    float O1 = d[1] * CT.cf[1][1] + d[3] * CT.cf[1][3] + d[5] * CT.cf[1][5] + d[7] * CT.cf[1][7];
    float O2 = d[1] * CT.cf[2][1] + d[3] * CT.cf[2][3] + d[5] * CT.cf[2][5] + d[7] * CT.cf[2][7];
    float O3 = d[1] * CT.cf[3][1] + d[3] * CT.cf[3][3] + d[5] * CT.cf[3][5] + d[7] * CT.cf[3][7];
    m[0] = E0 + O0; m[7] = E0 - O0;
    m[1] = E1 + O1; m[6] = E1 - O1;
    m[2] = E2 + O2; m[5] = E2 - O2;
    m[3] = E3 + O3; m[4] = E3 - O3;
}

} // namespace

// ---- LDS layout (bytes) ----------------------------------------------------
// lY    double[16*66] @0      8448  (row stride 66 dbl = 132 dw == 4 mod 32)
//   f32 overlays of lY region (written only after B2):
//   yR  f32 stride 68 @0     4352 ; cbR stride 36 @4352 1152 ; crR @5504 1152
// cbP   double[8*34]  @8448  2176
// crP   double[8*34]  @10624 2176
// qYfs  double[8*10]  @12800  640  (fs = scale/(tab*0.4); stride 10 => aligned + spread banks)
// qCfs  double[8*10]  @13440  640
// dsY   float [8*12]  @14080  384  (ds = tab*0.4*alpha pre-converted to f32; stride 12)
// dsC   float [8*12]  @14464  384
#define OFF_CBP 8448
#define OFF_CRP 10624
#define OFF_QYF 12800
#define OFF_QCF 13440
#define OFF_DSY 14080
#define OFF_DSC 14464
#define OFF_CBR 4352
#define OFF_CRR 5504
#define SMEM_BYTES 14848

__global__ void __launch_bounds__(256, 6) djpeg_kernel(
    const float* __restrict__ img,
    const float* __restrict__ ytab,
    const float* __restrict__ ctab,
    float* __restrict__ out)
{
    __shared__ __align__(16) unsigned char smem[SMEM_BYTES];
    double* lY   = (double*)(smem);
    double* cbP  = (double*)(smem + OFF_CBP);
    double* crP  = (double*)(smem + OFF_CRP);
    double* qYfs = (double*)(smem + OFF_QYF);
    double* qCfs = (double*)(smem + OFF_QCF);
    float*  dsY  = (float*)(smem + OFF_DSY);
    float*  dsC  = (float*)(smem + OFF_DSC);
    float*  yR   = (float*)(smem);
    float*  cbR  = (float*)(smem + OFF_CBR);
    float*  crR  = (float*)(smem + OFF_CRR);

    const int t  = threadIdx.x;
    const int X0 = blockIdx.x * 64;
    const int Y0 = blockIdx.y * 16;
    const int bi = blockIdx.z;

    // ---- quant factors: fs fp64 (pre-rint path), ds pre-converted f32 (post-rint path)
    if (t < 128) {
        const float* tab = (t < 64) ? ytab : ctab;
        double* qf = (t < 64) ? qYfs : qCfs;
        float*  df = (t < 64) ? dsY : dsC;
        int e = t & 63, u = e >> 3, v = e & 7;
        float tfacf = tab[e] * 0.4f;           // f32, matches reference weak-scalar promotion
        double tf = (double)tfacf;
        qf[v * 10 + u] = (double)CT.scalef[u][v] / tf;
        df[v * 12 + u] = (float)(tf * (double)CT.aof[u][v]);
    }

    // ---- phase 1: float4 RGB loads, fp64 YCbCr, Y -> LDS, 2x2-pooled chroma -> LDS
    {
        const int xq = t & 15, yb = t >> 4;    // thread = (row yb, col quad xq)
        size_t base = ((size_t)bi * 3) * IMG_HW + (size_t)(Y0 + yb) * IMG_W + X0 + xq * 4;
        const float4 rf = *(const float4*)(img + base);
        const float4 gf = *(const float4*)(img + base + IMG_HW);
        const float4 bf = *(const float4*)(img + base + 2 * IMG_HW);
        // fold *255 into the (f32-promoted) matrix constants; exact in fp64
        const double kYR =  (double)0.299f    * 255.0, kYG =  (double)0.587f    * 255.0, kYB =  (double)0.114f    * 255.0;
        const double kbR = -(double)0.168736f * 255.0, kbG = -(double)0.331264f * 255.0, kbB =  (double)0.5f      * 255.0;
        const double krR =  (double)0.5f      * 255.0, krG = -(double)0.418688f * 255.0, krB = -(double)0.081312f * 255.0;
        const float rr[4] = {rf.x, rf.y, rf.z, rf.w};
        const float gg[4] = {gf.x, gf.y, gf.z, gf.w};
        const float bb[4] = {bf.x, bf.y, bf.z, bf.w};
        double Yv[4], Cbv[4], Crv[4];
        #pragma unroll
        for (int i = 0; i < 4; i++) {
            double R = (double)rr[i], G = (double)gg[i], B = (double)bb[i];
            Yv[i]  = kYR * R + kYG * G + kYB * B;
            Cbv[i] = kbR * R + kbG * G + kbB * B + 128.0;
            Crv[i] = krR * R + krG * G + krB * B + 128.0;
        }
        double2* yw = (double2*)(lY + yb * 66 + xq * 4);
        yw[0] = make_double2(Yv[0], Yv[1]);
        yw[1] = make_double2(Yv[2], Yv[3]);
        // pool horizontally in-thread, vertically via row-partner lane (t^16)
        double cb0 = Cbv[0] + Cbv[1], cb1 = Cbv[2] + Cbv[3];
        double cr0 = Crv[0] + Crv[1], cr1 = Crv[2] + Crv[3];
        cb0 += __shfl_xor(cb0, 16);
        cb1 += __shfl_xor(cb1, 16);
        cr0 += __shfl_xor(cr0, 16);
        cr1 += __shfl_xor(cr1, 16);
        if ((yb & 1) == 0) {
            int pr = yb >> 1;
            *(double2*)(cbP + pr * 34 + xq * 2) = make_double2(cb0 * 0.25, cb1 * 0.25);
            *(double2*)(crP + pr * 34 + xq * 2) = make_double2(cr0 * 0.25, cr1 * 0.25);
        }
    }
    __syncthreads();  // B1

    // ---- DCT pipeline: 24 blocks x 8 lanes (t<192); transposes in-place via LDS
    const bool act = (t < 192);
    const int r = t & 7;
    double* blkd = lY;  const double* qfp = qYfs;  const float* dfp = dsY;
    float*  blkf = yR;
    int sD = 66, sF = 68;
    if (t < 128) {                    // 16 Y blocks
        int g = t >> 3, by = g >> 3, bx = g & 7;
        blkd = lY + (by * 8) * 66 + bx * 8;
        blkf = yR + (by * 8) * 68 + bx * 8;
    } else if (t < 192) {             // 4 cb + 4 cr blocks
        int c = t - 128, isCr = c >> 5, g2 = (c >> 3) & 3;
        blkd = (isCr ? crP : cbP) + g2 * 8;
        blkf = (isCr ? crR : cbR) + g2 * 8;
        qfp = qCfs; dfp = dsC;
        sD = 34; sF = 36;
    }

    float dq[8];
    if (act) {
        // stage A: row pass (fp64 butterfly). -128 shift only affects v=0 (sum C[y][v>0] = 0).
        const double* sp = blkd + r * sD;
        const double2 a01 = *(const double2*)(sp + 0);
        const double2 a23 = *(const double2*)(sp + 2);
        const double2 a45 = *(const double2*)(sp + 4);
        const double2 a67 = *(const double2*)(sp + 6);
        const double a[8] = {a01.x, a01.y, a23.x, a23.y, a45.x, a45.y, a67.x, a67.y};
        double s1[8];
        fwd8_d(a, s1);
        s1[0] -= 1024.0;   // 8 * 128

        // T1: in-place LDS transpose (own block region only; all stage-A reads of this
        // region were issued earlier by this same wave; DS ops complete in wave order)
        #pragma unroll
        for (int v = 0; v < 8; v++) blkd[v * sD + r] = s1[v];
        asm volatile("s_waitcnt lgkmcnt(0)" ::: "memory");
        const double* rp = blkd + r * sD;
        const double2 b01 = *(const double2*)(rp + 0);
        const double2 b23 = *(const double2*)(rp + 2);
        const double2 b45 = *(const double2*)(rp + 4);
        const double2 b67 = *(const double2*)(rp + 6);
        const double s2[8] = {b01.x, b01.y, b23.x, b23.y, b45.x, b45.y, b67.x, b67.y};

        // stage B: column pass (fp64 butterfly) + quant + diff_round + dequant
        double D[8];
        fwd8_d(s2, D);
        const double2 f01 = *(const double2*)(qfp + r * 10 + 0);
        const double2 f23 = *(const double2*)(qfp + r * 10 + 2);
        const double2 f45 = *(const double2*)(qfp + r * 10 + 4);
        const double2 f67 = *(const double2*)(qfp + r * 10 + 6);
        const double fsv[8] = {f01.x, f01.y, f23.x, f23.y, f45.x, f45.y, f67.x, f67.y};
        const float4 dA = *(const float4*)(dfp + r * 12);
        const float4 dB = *(const float4*)(dfp + r * 12 + 4);
        const float dsv[8] = {dA.x, dA.y, dA.z, dA.w, dB.x, dB.y, dB.z, dB.w};
        #pragma unroll
        for (int u = 0; u < 8; u++) {
            double xq = D[u] * fsv[u];
            double rq = rint(xq);
            float ef  = (float)(xq - rq);        // exact boundary decision stays fp64
            float rqf = (float)rq;               // post-rint path is continuous -> f32 ok
            dq[u] = (rqf + ef * ef * ef) * dsv[u];
        }
    }

    __syncthreads();  // B2: all fp64 LDS reads done chip-wide; f32 overlays now writable

    if (act) {
        // stage C: IDCT over u (fp32 butterfly); lane r holds column v=r
        float mc[8];
        inv8_f(dq, mc);

        // T2: in-place f32 LDS transpose in the overlay region (own block region only)
        #pragma unroll
        for (int p = 0; p < 8; p++) blkf[p * sF + r] = mc[p];
        asm volatile("s_waitcnt lgkmcnt(0)" ::: "memory");
        const float* fp_ = blkf + r * sF;
        const float4 m0 = *(const float4*)(fp_);
        const float4 m1 = *(const float4*)(fp_ + 4);
        const float mrow[8] = {m0.x, m0.y, m0.z, m0.w, m1.x, m1.y, m1.z, m1.w};

        // stage D: IDCT over v (fp32 butterfly), write spatial row r over the scratch
        float px[8];
        inv8_f(mrow, px);
        float* fw = blkf + r * sF;
        *(float4*)(fw)     = make_float4(fmaf(0.25f, px[0], 128.0f), fmaf(0.25f, px[1], 128.0f),
                                         fmaf(0.25f, px[2], 128.0f), fmaf(0.25f, px[3], 128.0f));
        *(float4*)(fw + 4) = make_float4(fmaf(0.25f, px[4], 128.0f), fmaf(0.25f, px[5], 128.0f),
                                         fmaf(0.25f, px[6], 128.0f), fmaf(0.25f, px[7], 128.0f));
    }
    __syncthreads();  // B3

    // ---- phase 3: upsample chroma, YCbCr->RGB, clip, /255, float4 stores
    {
        const int xq = t & 15, yb = t >> 4;
        const float4 yv  = *(const float4*)(yR + yb * 68 + xq * 4);
        const float2 cbv = *(const float2*)(cbR + (yb >> 1) * 36 + xq * 2);
        const float2 crv = *(const float2*)(crR + (yb >> 1) * 36 + xq * 2);
        const float yy[4]  = {yv.x, yv.y, yv.z, yv.w};
        const float cbs[2] = {cbv.x - 128.0f, cbv.y - 128.0f};
        const float crs[2] = {crv.x - 128.0f, crv.y - 128.0f};
        float R4[4], G4[4], B4[4];
        #pragma unroll
        for (int i = 0; i < 4; i++) {
            float Yv = yy[i], Cb = cbs[i >> 1], Cr = crs[i >> 1];
            float Rr = Yv + 1.402f * Cr;
            float Gg = Yv - 0.344136f * Cb - 0.714136f * Cr;
            float Bb = Yv + 1.772f * Cb;
            R4[i] = fminf(fmaxf(Rr, 0.0f), 255.0f) * (1.0f / 255.0f);
            G4[i] = fminf(fmaxf(Gg, 0.0f), 255.0f) * (1.0f / 255.0f);
            B4[i] = fminf(fmaxf(Bb, 0.0f), 255.0f) * (1.0f / 255.0f);
        }
        size_t base = ((size_t)bi * 3) * IMG_HW + (size_t)(Y0 + yb) * IMG_W + X0 + xq * 4;
        *(float4*)(out + base)              = make_float4(R4[0], R4[1], R4[2], R4[3]);
        *(float4*)(out + base + IMG_HW)     = make_float4(G4[0], G4[1], G4[2], G4[3]);
        *(float4*)(out + base + 2 * IMG_HW) = make_float4(B4[0], B4[1], B4[2], B4[3]);
    }
}

extern "C" void kernel_launch(void* const* d_in, const int* in_sizes, int n_in,
                              void* d_out, int out_size, void* d_ws, size_t ws_size,
                              hipStream_t stream) {
    (void)n_in; (void)out_size; (void)d_ws; (void)ws_size;
    const float* img = (const float*)d_in[0];
    const float* yt  = (const float*)d_in[1];
    const float* ct  = (const float*)d_in[2];
    float* out = (float*)d_out;
    int B = in_sizes[0] / (3 * IMG_HW);   // 32
    dim3 grid(IMG_W / 64, IMG_H / 16, B); // (8, 32, 32)
    djpeg_kernel<<<grid, dim3(256, 1, 1), 0, stream>>>(img, yt, ct, out);
}